// Round 2
// baseline (92.515 us; speedup 1.0000x reference)
//
#include <hip/hip_runtime.h>

#define MARGIN 0.5f
#define EPS 1e-6f
#define D 256

// Zero the scalar output (d_out is poisoned 0xAA before timing and never
// re-poisoned between graph replays — re-init every call).
__global__ void et_zero_kernel(float* __restrict__ out) {
    out[0] = 0.0f;
}

// Each wave handles 8 rows. lane = r_local*8 + c_sub:
//   r_local = lane>>3 selects the row within the group,
//   c_sub   = lane&7  selects a 16B chunk within a 128B row segment.
// Per iteration `it`, the 8 lanes of a row read its columns
// [it*32 + c_sub*4, +4) -> one contiguous 128B line per row, 8 rows per
// instruction: perfectly coalesced, lines fully consumed immediately.
// Row reduction = 3 butterfly steps (xor 1,2,4), all 8 rows in parallel.
__global__ __launch_bounds__(256) void et_triplet_kernel(
        const float* __restrict__ x,
        const float* __restrict__ y,
        const float* __restrict__ z,
        float* __restrict__ out,
        int n_groups) {                       // n_rows / 8
    const int lane    = threadIdx.x & 63;
    const int wib     = threadIdx.x >> 6;     // wave in block (0..3)
    const int wave    = blockIdx.x * 4 + wib;
    const int nwaves  = gridDim.x * 4;
    const int r_local = lane >> 3;            // 0..7
    const int c_sub   = lane & 7;             // 0..7

    float acc = 0.0f;

    for (int g = wave; g < n_groups; g += nwaves) {
        const int row = g * 8 + r_local;
        const size_t rowbase = (size_t)row * D + (size_t)c_sub * 4;

        float dp = 0.0f, dn = 0.0f;
        #pragma unroll
        for (int it = 0; it < 8; ++it) {
            const size_t idx = rowbase + (size_t)it * 32;   // 32 floats = 128B
            const float4 xv = *reinterpret_cast<const float4*>(x + idx);
            const float4 yv = *reinterpret_cast<const float4*>(y + idx);
            const float4 zv = *reinterpret_cast<const float4*>(z + idx);

            float d0 = xv.x - yv.x + EPS;
            float d1 = xv.y - yv.y + EPS;
            float d2 = xv.z - yv.z + EPS;
            float d3 = xv.w - yv.w + EPS;
            dp += d0 * d0 + d1 * d1 + d2 * d2 + d3 * d3;

            float e0 = xv.x - zv.x + EPS;
            float e1 = xv.y - zv.y + EPS;
            float e2 = xv.z - zv.z + EPS;
            float e3 = xv.w - zv.w + EPS;
            dn += e0 * e0 + e1 * e1 + e2 * e2 + e3 * e3;
        }

        // Reduce over the 8 chunk-lanes of each row; all rows in parallel.
        dp += __shfl_xor(dp, 1, 64);
        dn += __shfl_xor(dn, 1, 64);
        dp += __shfl_xor(dp, 2, 64);
        dn += __shfl_xor(dn, 2, 64);
        dp += __shfl_xor(dp, 4, 64);
        dn += __shfl_xor(dn, 4, 64);

        const float hinge = sqrtf(dp) + MARGIN - sqrtf(dn);
        if (c_sub == 0 && hinge > 0.0f) acc += hinge;  // once per row
    }

    // One full-wave butterfly, once per kernel.
    #pragma unroll
    for (int off = 32; off > 0; off >>= 1)
        acc += __shfl_xor(acc, off, 64);

    __shared__ float wsum[4];
    if (lane == 0) wsum[wib] = acc;
    __syncthreads();
    if (threadIdx.x == 0) {
        const float s = wsum[0] + wsum[1] + wsum[2] + wsum[3];
        atomicAdd(out, s);
    }
}

extern "C" void kernel_launch(void* const* d_in, const int* in_sizes, int n_in,
                              void* d_out, int out_size, void* d_ws, size_t ws_size,
                              hipStream_t stream) {
    const float* x = (const float*)d_in[0];
    const float* y = (const float*)d_in[1];
    const float* z = (const float*)d_in[2];
    float* out = (float*)d_out;

    const int n_rows   = in_sizes[0] / D;    // 131072
    const int n_groups = n_rows / 8;         // 16384 (N is a multiple of 8)

    et_zero_kernel<<<1, 1, 0, stream>>>(out);

    // One 8-row group per wave: 16384 waves = 4096 blocks of 4 waves.
    const int blocks = (n_groups + 3) / 4;
    et_triplet_kernel<<<blocks, 256, 0, stream>>>(x, y, z, out, n_groups);
}

// Round 3
// 77.729 us; speedup vs baseline: 1.1902x; 1.1902x over previous
//
#include <hip/hip_runtime.h>

#define MARGIN 0.5f
#define EPS 1e-6f
#define D 256

// Zero the scalar output (d_out is poisoned 0xAA before timing and never
// re-poisoned between graph replays — re-init every call).
__global__ void et_zero_kernel(float* __restrict__ out) {
    out[0] = 0.0f;
}

// 4 rows per group per wave. lane = r_local*16 + c_sub:
//   r_local = lane>>4 (0..3)  -> row within group
//   c_sub   = lane&15 (0..15) -> 16B chunk within a 256B row segment
// Per (it): a row's 16 lanes read a contiguous 256B chunk; 4 rows -> 4
// contiguous chunks at 1KB stride. Fully coalesced.
// Double-buffered across groups: loads for g+1 stay in flight while g is
// reduced. 24 float4 destinations (96 VGPR) sustained in flight per wave.
__global__ __launch_bounds__(256, 4) void et_triplet_kernel(
        const float* __restrict__ x,
        const float* __restrict__ y,
        const float* __restrict__ z,
        float* __restrict__ out,
        int n_groups) {                       // n_rows / 4
    const int lane    = threadIdx.x & 63;
    const int wib     = threadIdx.x >> 6;
    const int wave    = blockIdx.x * 4 + wib;
    const int nwaves  = gridDim.x * 4;
    const int r_local = lane >> 4;            // 0..3
    const int c_sub   = lane & 15;            // 0..15

    float acc = 0.0f;

    float4 Ax[4], Ay[4], Az[4], Bx[4], By[4], Bz[4];

#define LOADG(BX, BY, BZ, g_) do {                                          \
    const size_t rb_ = (size_t)((g_) * 4 + r_local) * D + (size_t)c_sub * 4;\
    _Pragma("unroll")                                                       \
    for (int it = 0; it < 4; ++it) {                                        \
        const size_t idx_ = rb_ + (size_t)it * 64;                          \
        BX[it] = *reinterpret_cast<const float4*>(x + idx_);                \
        BY[it] = *reinterpret_cast<const float4*>(y + idx_);                \
        BZ[it] = *reinterpret_cast<const float4*>(z + idx_);                \
    } } while (0)

#define COMPUTEG(BX, BY, BZ) do {                                           \
    float dp_ = 0.0f, dn_ = 0.0f;                                           \
    _Pragma("unroll")                                                       \
    for (int it = 0; it < 4; ++it) {                                        \
        float d0 = BX[it].x - BY[it].x + EPS;                               \
        float d1 = BX[it].y - BY[it].y + EPS;                               \
        float d2 = BX[it].z - BY[it].z + EPS;                               \
        float d3 = BX[it].w - BY[it].w + EPS;                               \
        dp_ += d0 * d0 + d1 * d1 + d2 * d2 + d3 * d3;                       \
        float e0 = BX[it].x - BZ[it].x + EPS;                               \
        float e1 = BX[it].y - BZ[it].y + EPS;                               \
        float e2 = BX[it].z - BZ[it].z + EPS;                               \
        float e3 = BX[it].w - BZ[it].w + EPS;                               \
        dn_ += e0 * e0 + e1 * e1 + e2 * e2 + e3 * e3;                       \
    }                                                                       \
    dp_ += __shfl_xor(dp_, 1, 64);  dn_ += __shfl_xor(dn_, 1, 64);          \
    dp_ += __shfl_xor(dp_, 2, 64);  dn_ += __shfl_xor(dn_, 2, 64);          \
    dp_ += __shfl_xor(dp_, 4, 64);  dn_ += __shfl_xor(dn_, 4, 64);          \
    dp_ += __shfl_xor(dp_, 8, 64);  dn_ += __shfl_xor(dn_, 8, 64);          \
    const float h_ = sqrtf(dp_) + MARGIN - sqrtf(dn_);                      \
    if (c_sub == 0 && h_ > 0.0f) acc += h_;                                 \
    } while (0)

    const int gpw = n_groups / nwaves;        // 8 with 1024 blocks
    int g = wave;

    if (gpw >= 2) {
        LOADG(Ax, Ay, Az, g);
        for (int p = 0; p < gpw / 2 - 1; ++p) {
            LOADG(Bx, By, Bz, g + nwaves);
            COMPUTEG(Ax, Ay, Az);
            LOADG(Ax, Ay, Az, g + 2 * nwaves);
            COMPUTEG(Bx, By, Bz);
            g += 2 * nwaves;
        }
        LOADG(Bx, By, Bz, g + nwaves);
        COMPUTEG(Ax, Ay, Az);
        COMPUTEG(Bx, By, Bz);
        g += 2 * nwaves;
    }
    // Tail (covers odd gpw / non-exact division; dead for 131072 rows).
    for (; g < n_groups; g += nwaves) {
        LOADG(Ax, Ay, Az, g);
        COMPUTEG(Ax, Ay, Az);
    }

#undef LOADG
#undef COMPUTEG

    // One full-wave butterfly, once per kernel.
    #pragma unroll
    for (int off = 32; off > 0; off >>= 1)
        acc += __shfl_xor(acc, off, 64);

    __shared__ float wsum[4];
    if (lane == 0) wsum[wib] = acc;
    __syncthreads();
    if (threadIdx.x == 0) {
        const float s = wsum[0] + wsum[1] + wsum[2] + wsum[3];
        atomicAdd(out, s);
    }
}

extern "C" void kernel_launch(void* const* d_in, const int* in_sizes, int n_in,
                              void* d_out, int out_size, void* d_ws, size_t ws_size,
                              hipStream_t stream) {
    const float* x = (const float*)d_in[0];
    const float* y = (const float*)d_in[1];
    const float* z = (const float*)d_in[2];
    float* out = (float*)d_out;

    const int n_rows   = in_sizes[0] / D;    // 131072
    const int n_groups = n_rows / 4;         // 32768

    et_zero_kernel<<<1, 1, 0, stream>>>(out);

    // Persistent grid: 1024 blocks x 4 waves = 4096 waves, 8 groups each.
    const int blocks = 1024;
    et_triplet_kernel<<<blocks, 256, 0, stream>>>(x, y, z, out, n_groups);
}

// Round 4
// 74.966 us; speedup vs baseline: 1.2341x; 1.0369x over previous
//
#include <hip/hip_runtime.h>

#define MARGIN 0.5f
#define EPS 1e-6f
#define D 256

// Main kernel: 4 rows per group per wave. lane = r_local*16 + c_sub:
//   r_local = lane>>4 (0..3)  -> row within group
//   c_sub   = lane&15 (0..15) -> 16B chunk within a 256B row segment
// Per it: each row's 16 lanes read a contiguous 256B chunk (2 full cache
// lines); 4 rows per instruction. Reduction: 8 shuffles per 4 rows.
// Occupancy-first: VGPR<=64 (single buffer) + 8192 waves = all wave slots.
// Each block writes ONE unconditional partial to ws[blockIdx.x] (no init
// needed, no atomics); a tail kernel reduces the 2048 partials.
__global__ __launch_bounds__(256, 8) void et_triplet_kernel(
        const float* __restrict__ x,
        const float* __restrict__ y,
        const float* __restrict__ z,
        float* __restrict__ ws,
        int n_groups) {                       // n_rows / 4
    const int lane    = threadIdx.x & 63;
    const int wib     = threadIdx.x >> 6;
    const int wave    = blockIdx.x * 4 + wib;
    const int nwaves  = gridDim.x * 4;
    const int r_local = lane >> 4;            // 0..3
    const int c_sub   = lane & 15;            // 0..15

    float acc = 0.0f;

    for (int g = wave; g < n_groups; g += nwaves) {
        const size_t rb = (size_t)(g * 4 + r_local) * D + (size_t)c_sub * 4;
        float4 vx[4], vy[4], vz[4];
        #pragma unroll
        for (int it = 0; it < 4; ++it) {
            const size_t idx = rb + (size_t)it * 64;     // 64 floats = 256B
            vx[it] = *reinterpret_cast<const float4*>(x + idx);
            vy[it] = *reinterpret_cast<const float4*>(y + idx);
            vz[it] = *reinterpret_cast<const float4*>(z + idx);
        }

        float dp = 0.0f, dn = 0.0f;
        #pragma unroll
        for (int it = 0; it < 4; ++it) {
            float d0 = vx[it].x - vy[it].x + EPS;
            float d1 = vx[it].y - vy[it].y + EPS;
            float d2 = vx[it].z - vy[it].z + EPS;
            float d3 = vx[it].w - vy[it].w + EPS;
            dp += d0 * d0 + d1 * d1 + d2 * d2 + d3 * d3;
            float e0 = vx[it].x - vz[it].x + EPS;
            float e1 = vx[it].y - vz[it].y + EPS;
            float e2 = vx[it].z - vz[it].z + EPS;
            float e3 = vx[it].w - vz[it].w + EPS;
            dn += e0 * e0 + e1 * e1 + e2 * e2 + e3 * e3;
        }

        // Reduce over the 16 chunk-lanes of each row; 4 rows in parallel.
        dp += __shfl_xor(dp, 1, 64);  dn += __shfl_xor(dn, 1, 64);
        dp += __shfl_xor(dp, 2, 64);  dn += __shfl_xor(dn, 2, 64);
        dp += __shfl_xor(dp, 4, 64);  dn += __shfl_xor(dn, 4, 64);
        dp += __shfl_xor(dp, 8, 64);  dn += __shfl_xor(dn, 8, 64);

        const float hinge = sqrtf(dp) + MARGIN - sqrtf(dn);
        if (c_sub == 0 && hinge > 0.0f) acc += hinge;   // once per row
    }

    // Wave butterfly once per kernel, then one store per block.
    #pragma unroll
    for (int off = 32; off > 0; off >>= 1)
        acc += __shfl_xor(acc, off, 64);

    __shared__ float wsum[4];
    if (lane == 0) wsum[wib] = acc;
    __syncthreads();
    if (threadIdx.x == 0)
        ws[blockIdx.x] = wsum[0] + wsum[1] + wsum[2] + wsum[3];
}

// Tail: reduce n_partials floats from ws into out[0] (unconditional write —
// no zero-init dispatch needed anywhere).
__global__ __launch_bounds__(256) void et_reduce_kernel(
        const float* __restrict__ ws, float* __restrict__ out, int n_partials) {
    const int lane = threadIdx.x & 63;
    const int wib  = threadIdx.x >> 6;
    float s = 0.0f;
    for (int i = threadIdx.x; i < n_partials; i += 256)
        s += ws[i];
    #pragma unroll
    for (int off = 32; off > 0; off >>= 1)
        s += __shfl_xor(s, off, 64);
    __shared__ float wsum[4];
    if (lane == 0) wsum[wib] = s;
    __syncthreads();
    if (threadIdx.x == 0)
        out[0] = wsum[0] + wsum[1] + wsum[2] + wsum[3];
}

extern "C" void kernel_launch(void* const* d_in, const int* in_sizes, int n_in,
                              void* d_out, int out_size, void* d_ws, size_t ws_size,
                              hipStream_t stream) {
    const float* x = (const float*)d_in[0];
    const float* y = (const float*)d_in[1];
    const float* z = (const float*)d_in[2];
    float* out = (float*)d_out;
    float* ws  = (float*)d_ws;

    const int n_rows   = in_sizes[0] / D;    // 131072
    const int n_groups = n_rows / 4;         // 32768

    // 2048 blocks x 4 waves = 8192 waves -> every wave slot on 256 CUs.
    const int blocks = 2048;
    et_triplet_kernel<<<blocks, 256, 0, stream>>>(x, y, z, ws, n_groups);
    et_reduce_kernel<<<1, 256, 0, stream>>>(ws, out, blocks);
}